// Round 7
// baseline (190.370 us; speedup 1.0000x reference)
//
#include <hip/hip_runtime.h>

#define BATCH 4096
#define DIM 4096
#define NSPLIT 64
#define ROWS_PB 128
#define NCHUNK 32            // BATCH / ROWS_PB
#define BN_EPS 1e-3f

typedef __attribute__((ext_vector_type(8))) short bf16x8;
typedef __attribute__((ext_vector_type(8))) unsigned short ushort8;
typedef __attribute__((ext_vector_type(4))) float f32x4;

__device__ inline unsigned short f2bf(float f) {
    union { float f; unsigned int u; } c; c.f = f;
    unsigned int u = c.u;
    u += 0x7FFFu + ((u >> 16) & 1u);   // round-to-nearest-even
    return (unsigned short)(u >> 16);
}

__device__ inline float bf2f(unsigned short h) {
    union { unsigned int u; float f; } c;
    c.u = (unsigned int)h << 16;
    return c.f;
}

// K0: pure streaming convert. x fp32 (64 MB, the only cold HBM read in the
// pipeline) -> bf16 (32 MB) stored in the ODD 64-row half of each 128-row
// chunk tile of `out` (bytes K1's y-packing never touches). Copy-kernel
// shape: tiny VGPR, no LDS, no barriers -> max read-issue occupancy.
// Chunk c's bf16 x (128 rows x 4096 cols) lives at ushort index
// (c<<20) + (1<<19) of out-viewed-as-ushort, linear row-major.
__global__ __launch_bounds__(256) void x_cvt(
    const float* __restrict__ x, float* __restrict__ out)
{
    unsigned int tid = blockIdx.x * 256u + threadIdx.x;   // 524288 threads
    unsigned short* us = (unsigned short*)out;
    #pragma unroll
    for (int it = 0; it < 8; it++) {
        unsigned int e4 = tid + (unsigned int)it * 524288u;  // float4 index, 4.19M total
        unsigned int e  = e4 * 4u;                           // element index
        unsigned int c  = e >> 19;                           // chunk (128 rows = 524288 elems)
        unsigned int o  = e & 524287u;                       // offset within chunk
        float4 v = *(const float4*)(x + e);
        ushort4 u;
        u.x = f2bf(v.x); u.y = f2bf(v.y); u.z = f2bf(v.z); u.w = f2bf(v.w);
        *(ushort4*)(us + ((size_t)c << 20) + (1u << 19) + o) = u;
    }
}

// K1: GEMM once from L3-hot bf16 x. A-fragments: 4 x 16B direct loads (no
// f2bf on the x path), issued before W staging. Emits per-block column
// sum/sumsq partials into part (1 MiB validated ws) and y as bf16 packed
// into the EVEN 64-row half of the block's out-tile (R4 layout, unchanged).
// Bias dropped: cancels exactly under BatchNorm mean subtraction.
__global__ __launch_bounds__(256) void gemm_stats(
    const float* __restrict__ w, float* __restrict__ part,
    float* __restrict__ out)
{
    __shared__ unsigned short wt[64][72];
    __shared__ float red1[4][64], red2[4][64];

    const int s  = blockIdx.y;
    const int r0 = blockIdx.x * ROWS_PB;
    const int t  = threadIdx.x;
    const int lane = t & 63, wave = t >> 6;
    const int quad = lane >> 4, l16 = lane & 15;

    // x-fragment loads first: L3-hot bf16, one 16B load per (rt,kk)
    const unsigned short* xb = (const unsigned short*)out;
    const size_t cbase = ((size_t)blockIdx.x << 20) + (1u << 19);
    bf16x8 af[2][2];
    #pragma unroll
    for (int rt = 0; rt < 2; rt++)
        #pragma unroll
        for (int kk = 0; kk < 2; kk++)
            af[rt][kk] = *(const bf16x8*)(
                xb + cbase + (size_t)(wave*32 + rt*16 + l16) * DIM
                   + s*64 + kk*32 + quad*8);

    // stage W_s transposed (fp32 -> bf16), coalesced float4 reads
    for (int i = t; i < 1024; i += 256) {
        int k = i >> 4, c4 = i & 15;
        float4 v = *(const float4*)(w + (size_t)(s*64 + k) * DIM + s*64 + c4*4);
        wt[c4*4 + 0][k] = f2bf(v.x);
        wt[c4*4 + 1][k] = f2bf(v.y);
        wt[c4*4 + 2][k] = f2bf(v.z);
        wt[c4*4 + 3][k] = f2bf(v.w);
    }
    __syncthreads();

    bf16x8 bfr[4][2];
    #pragma unroll
    for (int ct = 0; ct < 4; ct++)
        #pragma unroll
        for (int kk = 0; kk < 2; kk++)
            bfr[ct][kk] = *(const bf16x8*)&wt[ct*16 + l16][kk*32 + quad*8];

    f32x4 acc[2][4];
    #pragma unroll
    for (int rt = 0; rt < 2; rt++)
        #pragma unroll
        for (int ct = 0; ct < 4; ct++)
            acc[rt][ct] = (f32x4){0.f, 0.f, 0.f, 0.f};

    #pragma unroll
    for (int kk = 0; kk < 2; kk++)
        #pragma unroll
        for (int rt = 0; rt < 2; rt++)
            #pragma unroll
            for (int ct = 0; ct < 4; ct++)
                acc[rt][ct] = __builtin_amdgcn_mfma_f32_16x16x32_bf16(
                    af[rt][kk], bfr[ct][kk], acc[rt][ct], 0, 0, 0);

    // pack y -> bf16 into the block's own EVEN-half out-tile (R4 layout)
    #pragma unroll
    for (int j = 0; j < 4; j++) {
        const int f0 = 2*j, f1 = 2*j + 1;
        const f32x4 a0 = acc[f0 >> 2][f0 & 3];
        const f32x4 a1 = acc[f1 >> 2][f1 & 3];
        ushort8 pk;
        pk[0] = f2bf(a0[0]); pk[1] = f2bf(a0[1]);
        pk[2] = f2bf(a0[2]); pk[3] = f2bf(a0[3]);
        pk[4] = f2bf(a1[0]); pk[5] = f2bf(a1[1]);
        pk[6] = f2bf(a1[2]); pk[7] = f2bf(a1[3]);
        int u = j*256 + t;   // 1024 ushort8 units = 64 rows x 16 units
        unsigned short* dst =
            (unsigned short*)(out + (size_t)(r0 + (u >> 4)) * DIM + s*64)
            + (u & 15) * 8;
        *(ushort8*)dst = pk;
    }

    // per-thread column partials -> wave shuffle -> cross-wave LDS -> part
    float s1[4], s2[4];
    #pragma unroll
    for (int ct = 0; ct < 4; ct++) { s1[ct] = 0.f; s2[ct] = 0.f; }
    #pragma unroll
    for (int rt = 0; rt < 2; rt++)
        #pragma unroll
        for (int ct = 0; ct < 4; ct++)
            #pragma unroll
            for (int r = 0; r < 4; r++) {
                float v = acc[rt][ct][r];
                s1[ct] += v; s2[ct] += v * v;
            }
    #pragma unroll
    for (int ct = 0; ct < 4; ct++) {
        float a = s1[ct], b = s2[ct];
        a += __shfl_xor(a, 16); b += __shfl_xor(b, 16);
        a += __shfl_xor(a, 32); b += __shfl_xor(b, 32);
        if (quad == 0) {
            red1[wave][ct*16 + l16] = a;
            red2[wave][ct*16 + l16] = b;
        }
    }
    __syncthreads();
    if (t < 64) {
        float a = red1[0][t] + red1[1][t] + red1[2][t] + red1[3][t];
        float b = red2[0][t] + red2[1][t] + red2[2][t] + red2[3][t];
        size_t base = (size_t)(s * NCHUNK + blockIdx.x) * 128;
        part[base + t]      = a;
        part[base + 64 + t] = b;
    }
}

// K2: finalize stats (parallel reduce), read back the block's own bf16 y
// tile (L3-hot), BN + ReLU, fp32 scatter store over the full tile (this
// also overwrites the odd-half x-bf16 scratch with final values).
__global__ __launch_bounds__(256) void bn_apply(
    const float* __restrict__ part, const float* __restrict__ gamma,
    const float* __restrict__ beta, float* __restrict__ out)
{
    __shared__ float redA[4][64], redB[4][64];
    __shared__ float scol[64], shcol[64];

    const int s  = blockIdx.y;
    const int r0 = blockIdx.x * ROWS_PB;
    const int t  = threadIdx.x;
    const int lane = t & 63, wave = t >> 6;
    const int quad = lane >> 4, l16 = lane & 15;

    // load own y tile early (issue all 4 loads before the reduce)
    ushort8 yv[4];
    #pragma unroll
    for (int j = 0; j < 4; j++) {
        int u = j*256 + t;
        const unsigned short* src =
            (const unsigned short*)(out + (size_t)(r0 + (u >> 4)) * DIM + s*64)
            + (u & 15) * 8;
        yv[j] = *(const ushort8*)src;
    }

    // parallel part-reduce: wave g covers chunks g*8..g*8+7, col = lane
    {
        float a = 0.f, b = 0.f;
        #pragma unroll
        for (int p8 = 0; p8 < 8; p8++) {
            int p = wave*8 + p8;
            size_t base = (size_t)(s * NCHUNK + p) * 128;
            a += part[base + lane];
            b += part[base + 64 + lane];
        }
        redA[wave][lane] = a;
        redB[wave][lane] = b;
    }

    // all global loads (y + part) must have landed before any thread stores
    asm volatile("s_waitcnt vmcnt(0)" ::: "memory");
    __syncthreads();

    if (t < 64) {
        float a = redA[0][t] + redA[1][t] + redA[2][t] + redA[3][t];
        float b = redB[0][t] + redB[1][t] + redB[2][t] + redB[3][t];
        float mean = a * (1.f / BATCH);
        float var  = b * (1.f / BATCH) - mean * mean;
        float rstd = rsqrtf(var + BN_EPS);
        float sc = gamma[s*64 + t] * rstd;
        scol[t]  = sc;
        shcol[t] = beta[s*64 + t] - mean * sc;
    }
    __syncthreads();

    #pragma unroll
    for (int j = 0; j < 4; j++) {
        #pragma unroll
        for (int h = 0; h < 2; h++) {
            const int f  = 2*j + h;
            const int rt = f >> 2, ct = f & 3;
            const int col = ct*16 + l16;
            const float sc = scol[col], sh = shcol[col];
            #pragma unroll
            for (int r = 0; r < 4; r++) {
                float v = fmaxf(fmaf(bf2f((unsigned short)yv[j][h*4 + r]), sc, sh), 0.f);
                int row = r0 + wave*32 + rt*16 + quad*4 + r;
                out[(size_t)row * DIM + s*64 + col] = v;
            }
        }
    }
}

extern "C" void kernel_launch(void* const* d_in, const int* in_sizes, int n_in,
                              void* d_out, int out_size, void* d_ws, size_t ws_size,
                              hipStream_t stream) {
    const float* x     = (const float*)d_in[0];
    const float* w     = (const float*)d_in[1];
    // d_in[2] = bias: cancels exactly in BatchNorm (mean subtraction) — unused
    const float* gamma = (const float*)d_in[3];
    const float* beta  = (const float*)d_in[4];
    float* out  = (float*)d_out;
    float* part = (float*)d_ws;    // 1 MiB — the baseline-validated footprint

    x_cvt     <<<dim3(2048),            256, 0, stream>>>(x, out);
    gemm_stats<<<dim3(NCHUNK, NSPLIT),  256, 0, stream>>>(w, part, out);
    bn_apply  <<<dim3(NCHUNK, NSPLIT),  256, 0, stream>>>(part, gamma, beta, out);
}

// Round 8
// 178.040 us; speedup vs baseline: 1.0693x; 1.0693x over previous
//
#include <hip/hip_runtime.h>

#define BATCH 4096
#define DIM 4096
#define NSPLIT 64
#define ROWS_PB 128
#define NCHUNK 32            // BATCH / ROWS_PB
#define BN_EPS 1e-3f

typedef __attribute__((ext_vector_type(8))) short bf16x8;
typedef __attribute__((ext_vector_type(8))) unsigned short ushort8;
typedef __attribute__((ext_vector_type(4))) float f32x4;

__device__ inline unsigned short f2bf(float f) {
    union { float f; unsigned int u; } c; c.f = f;
    unsigned int u = c.u;
    u += 0x7FFFu + ((u >> 16) & 1u);   // round-to-nearest-even
    return (unsigned short)(u >> 16);
}

__device__ inline float bf2f(unsigned short h) {
    union { unsigned int u; float f; } c;
    c.u = (unsigned int)h << 16;
    return c.f;
}

// K1: GEMM once, latency-lean.
//  - A-fragments loaded DIRECTLY global->reg (8 independent float4 loads/lane;
//    no X LDS staging, no barrier on the X path).
//  - W block staged via LDS (transposed) — only 9.2 KB; total LDS 11.5 KB.
//  - Emits per-block column sum/sumsq partials into part (1 MiB validated ws)
//    and y as bf16 packed into the block's OWN out-tile (rows r0..r0+63 of its
//    128x64 region => 64 rows x 16 ushort8 units), 16B/lane coalesced.
//  - Bias dropped: cancels exactly under BatchNorm mean subtraction.
__global__ __launch_bounds__(256) void gemm_stats(
    const float* __restrict__ x, const float* __restrict__ w,
    float* __restrict__ part, float* __restrict__ out)
{
    __shared__ unsigned short wt[64][72];
    __shared__ float red1[4][64], red2[4][64];

    const int s  = blockIdx.y;
    const int r0 = blockIdx.x * ROWS_PB;
    const int t  = threadIdx.x;
    const int lane = t & 63, wave = t >> 6;
    const int quad = lane >> 4, l16 = lane & 15;

    // stage W_s transposed (fp32 -> bf16), coalesced float4 reads
    for (int i = t; i < 1024; i += 256) {
        int k = i >> 4, c4 = i & 15;
        float4 v = *(const float4*)(w + (size_t)(s*64 + k) * DIM + s*64 + c4*4);
        wt[c4*4 + 0][k] = f2bf(v.x);
        wt[c4*4 + 1][k] = f2bf(v.y);
        wt[c4*4 + 2][k] = f2bf(v.z);
        wt[c4*4 + 3][k] = f2bf(v.w);
    }

    // A-fragments: direct global->reg, 8 independent 16B loads (full MLP)
    float4 xv[2][2][2];
    #pragma unroll
    for (int rt = 0; rt < 2; rt++)
        #pragma unroll
        for (int kk = 0; kk < 2; kk++)
            #pragma unroll
            for (int h = 0; h < 2; h++)
                xv[rt][kk][h] = *(const float4*)(
                    x + (size_t)(r0 + wave*32 + rt*16 + l16) * DIM
                      + s*64 + kk*32 + quad*8 + h*4);

    __syncthreads();   // wt ready

    bf16x8 af[2][2], bfr[4][2];
    #pragma unroll
    for (int rt = 0; rt < 2; rt++)
        #pragma unroll
        for (int kk = 0; kk < 2; kk++) {
            bf16x8 a;
            a[0] = (short)f2bf(xv[rt][kk][0].x);
            a[1] = (short)f2bf(xv[rt][kk][0].y);
            a[2] = (short)f2bf(xv[rt][kk][0].z);
            a[3] = (short)f2bf(xv[rt][kk][0].w);
            a[4] = (short)f2bf(xv[rt][kk][1].x);
            a[5] = (short)f2bf(xv[rt][kk][1].y);
            a[6] = (short)f2bf(xv[rt][kk][1].z);
            a[7] = (short)f2bf(xv[rt][kk][1].w);
            af[rt][kk] = a;
        }
    #pragma unroll
    for (int ct = 0; ct < 4; ct++)
        #pragma unroll
        for (int kk = 0; kk < 2; kk++)
            bfr[ct][kk] = *(const bf16x8*)&wt[ct*16 + l16][kk*32 + quad*8];

    f32x4 acc[2][4];
    #pragma unroll
    for (int rt = 0; rt < 2; rt++)
        #pragma unroll
        for (int ct = 0; ct < 4; ct++)
            acc[rt][ct] = (f32x4){0.f, 0.f, 0.f, 0.f};

    #pragma unroll
    for (int kk = 0; kk < 2; kk++)
        #pragma unroll
        for (int rt = 0; rt < 2; rt++)
            #pragma unroll
            for (int ct = 0; ct < 4; ct++)
                acc[rt][ct] = __builtin_amdgcn_mfma_f32_16x16x32_bf16(
                    af[rt][kk], bfr[ct][kk], acc[rt][ct], 0, 0, 0);

    // pack y -> bf16 into the block's own out-tile scratch (no race: this
    // exact region is read back only by K2's block (s, blockIdx.x))
    #pragma unroll
    for (int j = 0; j < 4; j++) {
        const int f0 = 2*j, f1 = 2*j + 1;
        const f32x4 a0 = acc[f0 >> 2][f0 & 3];
        const f32x4 a1 = acc[f1 >> 2][f1 & 3];
        ushort8 pk;
        pk[0] = f2bf(a0[0]); pk[1] = f2bf(a0[1]);
        pk[2] = f2bf(a0[2]); pk[3] = f2bf(a0[3]);
        pk[4] = f2bf(a1[0]); pk[5] = f2bf(a1[1]);
        pk[6] = f2bf(a1[2]); pk[7] = f2bf(a1[3]);
        int u = j*256 + t;   // 1024 ushort8 units = 64 rows x 16 units
        unsigned short* dst =
            (unsigned short*)(out + (size_t)(r0 + (u >> 4)) * DIM + s*64)
            + (u & 15) * 8;
        *(ushort8*)dst = pk;
    }

    // per-thread column partials -> wave shuffle -> cross-wave LDS -> part
    float s1[4], s2[4];
    #pragma unroll
    for (int ct = 0; ct < 4; ct++) { s1[ct] = 0.f; s2[ct] = 0.f; }
    #pragma unroll
    for (int rt = 0; rt < 2; rt++)
        #pragma unroll
        for (int ct = 0; ct < 4; ct++)
            #pragma unroll
            for (int r = 0; r < 4; r++) {
                float v = acc[rt][ct][r];
                s1[ct] += v; s2[ct] += v * v;
            }
    #pragma unroll
    for (int ct = 0; ct < 4; ct++) {
        float a = s1[ct], b = s2[ct];
        a += __shfl_xor(a, 16); b += __shfl_xor(b, 16);
        a += __shfl_xor(a, 32); b += __shfl_xor(b, 32);
        if (quad == 0) {
            red1[wave][ct*16 + l16] = a;
            red2[wave][ct*16 + l16] = b;
        }
    }
    __syncthreads();
    if (t < 64) {
        float a = red1[0][t] + red1[1][t] + red1[2][t] + red1[3][t];
        float b = red2[0][t] + red2[1][t] + red2[2][t] + red2[3][t];
        size_t base = (size_t)(s * NCHUNK + blockIdx.x) * 128;
        part[base + t]      = a;
        part[base + 64 + t] = b;
    }
}

// K2: finalize stats (parallel reduce over all 256 threads), read back the
// block's own bf16 y tile, BN + ReLU, fp32 scatter store. Explicit
// vmcnt(0)+barrier orders tile-read before any tile-overwrite.
__global__ __launch_bounds__(256) void bn_apply(
    const float* __restrict__ part, const float* __restrict__ gamma,
    const float* __restrict__ beta, float* __restrict__ out)
{
    __shared__ float redA[4][64], redB[4][64];
    __shared__ float scol[64], shcol[64];

    const int s  = blockIdx.y;
    const int r0 = blockIdx.x * ROWS_PB;
    const int t  = threadIdx.x;
    const int lane = t & 63, wave = t >> 6;
    const int quad = lane >> 4, l16 = lane & 15;

    // load own y tile early (issue all 4 loads before the reduce)
    ushort8 yv[4];
    #pragma unroll
    for (int j = 0; j < 4; j++) {
        int u = j*256 + t;
        const unsigned short* src =
            (const unsigned short*)(out + (size_t)(r0 + (u >> 4)) * DIM + s*64)
            + (u & 15) * 8;
        yv[j] = *(const ushort8*)src;
    }

    // parallel part-reduce: wave g covers chunks g*8..g*8+7, col = lane
    {
        float a = 0.f, b = 0.f;
        #pragma unroll
        for (int p8 = 0; p8 < 8; p8++) {
            int p = wave*8 + p8;
            size_t base = (size_t)(s * NCHUNK + p) * 128;
            a += part[base + lane];
            b += part[base + 64 + lane];
        }
        redA[wave][lane] = a;
        redB[wave][lane] = b;
    }

    // all global loads (y + part) must have landed before any thread stores
    asm volatile("s_waitcnt vmcnt(0)" ::: "memory");
    __syncthreads();

    if (t < 64) {
        float a = redA[0][t] + redA[1][t] + redA[2][t] + redA[3][t];
        float b = redB[0][t] + redB[1][t] + redB[2][t] + redB[3][t];
        float mean = a * (1.f / BATCH);
        float var  = b * (1.f / BATCH) - mean * mean;
        float rstd = rsqrtf(var + BN_EPS);
        float sc = gamma[s*64 + t] * rstd;
        scol[t]  = sc;
        shcol[t] = beta[s*64 + t] - mean * sc;
    }
    __syncthreads();

    #pragma unroll
    for (int j = 0; j < 4; j++) {
        #pragma unroll
        for (int h = 0; h < 2; h++) {
            const int f  = 2*j + h;
            const int rt = f >> 2, ct = f & 3;
            const int col = ct*16 + l16;
            const float sc = scol[col], sh = shcol[col];
            #pragma unroll
            for (int r = 0; r < 4; r++) {
                float v = fmaxf(fmaf(bf2f((unsigned short)yv[j][h*4 + r]), sc, sh), 0.f);
                int row = r0 + wave*32 + rt*16 + quad*4 + r;
                out[(size_t)row * DIM + s*64 + col] = v;
            }
        }
    }
}

extern "C" void kernel_launch(void* const* d_in, const int* in_sizes, int n_in,
                              void* d_out, int out_size, void* d_ws, size_t ws_size,
                              hipStream_t stream) {
    const float* x     = (const float*)d_in[0];
    const float* w     = (const float*)d_in[1];
    // d_in[2] = bias: cancels exactly in BatchNorm (mean subtraction) — unused
    const float* gamma = (const float*)d_in[3];
    const float* beta  = (const float*)d_in[4];
    float* out  = (float*)d_out;
    float* part = (float*)d_ws;    // 1 MiB — the baseline-validated footprint

    gemm_stats<<<dim3(NCHUNK, NSPLIT), 256, 0, stream>>>(x, w, part, out);
    bn_apply<<<dim3(NCHUNK, NSPLIT), 256, 0, stream>>>(part, gamma, beta, out);
}